// Round 11
// baseline (15950.011 us; speedup 1.0000x reference)
//
#include <hip/hip_runtime.h>
#include <math.h>

#define HID   256
#define TLEN  512
#define NTHR  1024
#define GSIZE 8
#define NGRP  32
#define BBG   256            // batches per group (2 cohorts x 128)

// h exchange: per group 8 planes [cohort2][buf2][sel2] of 8mt*8kc*512 u16
#define PLANE2   (8 * 8 * 512)                   // 32768 u16 = 64 KiB
#define GRP_U16  ((size_t)8 * PLANE2)
#define HEX_U16  ((size_t)NGRP * GRP_U16)        // 8M u16 = 16 MiB
#define FLAGS_OFF (HEX_U16 * 2)                  // bytes
#define FLAGSET   16                             // u32 per (g,cohort) set (64B pad)
#define WS_NEEDED (FLAGS_OFF + (size_t)NGRP * 2 * FLAGSET * 4)

typedef __attribute__((ext_vector_type(8))) short short8;
typedef __attribute__((ext_vector_type(4))) float f32x4;

typedef union {
    float4 f;
    uint4  u;
    short8 s;
} v16u;

static __device__ __forceinline__ unsigned short f2bf_rne(float x) {
    unsigned int u = __float_as_uint(x);
    unsigned int r = (u + 0x7FFFu + ((u >> 16) & 1u)) >> 16;
    return (unsigned short)r;
}
static __device__ __forceinline__ float bf2f(unsigned short h) {
    return __uint_as_float(((unsigned int)h) << 16);
}
static __device__ __forceinline__ float sigf(float x) {
    return 1.0f / (1.0f + __expf(-x));
}
static __device__ __forceinline__ float tanhf_fast(float x) {
    return 1.0f - 2.0f / (1.0f + __expf(2.0f * x));
}

// one dwordx4 load, L1-bypass (sc0), no wait — caller waits via vmcnt
static __device__ __forceinline__ void issue_sc0(const void* p, float4& a) {
    asm volatile("global_load_dwordx4 %0, %1, off sc0"
                 : "=&v"(a) : "v"(p) : "memory");
}

// ============ cooperative weight-stationary, dual-cohort pipeline ============
__global__ __launch_bounds__(NTHR, 4) void lstm_coop3(
    const float* __restrict__ x,
    const float* __restrict__ W_ih,
    const float* __restrict__ W_hh,
    const float* __restrict__ b_ih,
    const float* __restrict__ b_hh,
    const float* __restrict__ W_fc,
    const float* __restrict__ b_fc,
    unsigned short* __restrict__ hexw,  // ws: split-bf16 h exchange planes
    unsigned int* __restrict__ flags,   // ws: [NGRP][2][FLAGSET], memset 0
    float* __restrict__ out)
{
    const int tid  = threadIdx.x;
    const int bid  = blockIdx.x;
    const int xcd  = bid & 7;          // round-robin XCD mapping
    const int p    = (bid >> 3) & 7;   // producer index within group
    const int gsub = bid >> 6;         // 0..3
    const int g    = xcd * 4 + gsub;   // group 0..31 (XCD-local)
    const int wv   = tid >> 6;         // 0..15
    const int lane = tid & 63;
    const int l15  = lane & 15;
    const int l4   = lane >> 4;
    const int cohort = wv >> 3;        // 0 = waves 0-7, 1 = waves 8-15
    const int mtc  = wv & 7;           // M-tile within cohort (16 batches)
    const int bbase = g * BBG + cohort * 128;

    __shared__ unsigned short whi_s[64 * 512];  // 64 KiB  B-frags hi
    __shared__ unsigned short wlo_s[64 * 512];  // 64 KiB  B-frags lo
    __shared__ float wfc_s[HID];
    __shared__ unsigned int cnt[2];             // per-cohort arrival counters

    // ---- stage this block's 128 gate-rows into LDS (split bf16, B-frag order) ----
    #pragma unroll
    for (int i = 0; i < 4; ++i) {
        int tile = wv * 4 + i;            // 0..63 = nt*8 + kc
        int nt = tile >> 3, kc = tile & 7;
        int q = nt >> 1, half = nt & 1;
        int grow = q * 256 + p * 32 + half * 16 + l15;
        int k0 = kc * 32 + l4 * 8;
        const float* src = W_hh + (size_t)grow * HID + k0;
        float4 wa = *(const float4*)src;
        float4 wb = *(const float4*)(src + 4);
        float ff[8] = {wa.x, wa.y, wa.z, wa.w, wb.x, wb.y, wb.z, wb.w};
        short8 hi8, lo8;
        #pragma unroll
        for (int e = 0; e < 8; ++e) {
            unsigned int u = __float_as_uint(ff[e]);
            hi8[e] = (short)(u >> 16);
            float res = ff[e] - __uint_as_float(u & 0xffff0000u);
            lo8[e] = (short)f2bf_rne(res);
        }
        *(short8*)&whi_s[tile * 512 + lane * 8] = hi8;
        *(short8*)&wlo_s[tile * 512 + lane * 8] = lo8;
    }
    if (tid < HID) wfc_s[tid] = W_fc[tid];
    if (tid < 2)   cnt[tid] = 0;

    // per-lane gate constants: nt = q*2+half -> grow
    float biasv[8], wihv[8];
    #pragma unroll
    for (int nt = 0; nt < 8; ++nt) {
        int grow = (nt >> 1) * 256 + p * 32 + (nt & 1) * 16 + l15;
        biasv[nt] = b_ih[grow] + b_hh[grow];
        wihv[nt]  = W_ih[grow];
    }
    const float bfc = b_fc[0];

    float c_r[2][4];
    #pragma unroll
    for (int half = 0; half < 2; ++half)
        #pragma unroll
        for (int r = 0; r < 4; ++r) c_r[half][r] = 0.0f;

    unsigned int* flgc = flags + (g * 2 + cohort) * FLAGSET;
    unsigned short* const cbase = hexw + ((size_t)g * 8 + cohort * 4) * PLANE2;
    // plane(buf,sel) = cbase + (buf*2+sel)*PLANE2

    __syncthreads();   // weights + cnt ready; last block-wide barrier

    // ================= step 0: gates = bias + x*wih (h=0) =================
    {
        float dreg[4];
        #pragma unroll
        for (int r = 0; r < 4; ++r) dreg[r] = x[bbase + mtc * 16 + l4 * 4 + r];

        unsigned short* hiw = cbase + (1 * 2 + 0) * PLANE2;  // h(1) -> buf 1
        unsigned short* low = cbase + (1 * 2 + 1) * PLANE2;
        #pragma unroll
        for (int half = 0; half < 2; ++half) {
            #pragma unroll
            for (int r = 0; r < 4; ++r) {
                float gi = fmaf(dreg[r], wihv[0 + half], biasv[0 + half]);
                float gf = fmaf(dreg[r], wihv[2 + half], biasv[2 + half]);
                float gg = fmaf(dreg[r], wihv[4 + half], biasv[4 + half]);
                float go = fmaf(dreg[r], wihv[6 + half], biasv[6 + half]);
                float c = fmaf(sigf(gf), c_r[half][r], sigf(gi) * tanhf_fast(gg));
                c_r[half][r] = c;
                float h = sigf(go) * tanhf_fast(c);
                int lane_d = l4 * 4 + r + 16 * (half * 2 + (l15 >> 3));
                int idx = (mtc * 8 + p) * 512 + lane_d * 8 + (l15 & 7);
                unsigned int u = __float_as_uint(h);
                hiw[idx] = (unsigned short)(u >> 16);
                float res = h - __uint_as_float(u & 0xffff0000u);
                low[idx] = f2bf_rne(res);
            }
        }
        asm volatile("s_waitcnt vmcnt(0)" ::: "memory");   // own stores drained
        if (lane == 0) atomicAdd(&cnt[cohort], 1u);
        if (mtc == 0 && lane == 0) {
            int guard = 0;
            while (__hip_atomic_load(&cnt[cohort], __ATOMIC_RELAXED,
                                     __HIP_MEMORY_SCOPE_WORKGROUP) < 8u) {
                if (++guard > (1 << 20)) break;
            }
            __hip_atomic_store(&flgc[p], 1u, __ATOMIC_RELEASE, __HIP_MEMORY_SCOPE_AGENT);
        }
    }

    // ================= steps 1..511 =================
    #pragma unroll 1
    for (int t = 1; t < TLEN; ++t) {
        // wait for all 8 shares of h(t) — per-wave poll, no block barrier
        {
            int guard = 0;
            for (;;) {
                unsigned int v = __hip_atomic_load(&flgc[lane & 7], __ATOMIC_RELAXED,
                                                   __HIP_MEMORY_SCOPE_AGENT);
                if (__all(v >= (unsigned int)t)) break;
                if (++guard > (1 << 20)) break;
            }
        }

        const unsigned short* hir = cbase + ((t & 1) * 2 + 0) * PLANE2
                                  + (mtc * 8) * 512 + lane * 8;
        const unsigned short* lor = cbase + ((t & 1) * 2 + 1) * PLANE2
                                  + (mtc * 8) * 512 + lane * 8;

        f32x4 acc[8];
        #pragma unroll
        for (int nt = 0; nt < 8; ++nt)
            #pragma unroll
            for (int r = 0; r < 4; ++r) acc[nt][r] = 0.0f;

        float dsum = 0.0f;
        v16u pfh[2], pfl[2];
        issue_sc0(hir, pfh[0].f);
        issue_sc0(lor, pfl[0].f);

        #pragma unroll
        for (int kc = 0; kc < 8; ++kc) {
            if (kc < 7) {
                issue_sc0(hir + (kc + 1) * 512, pfh[(kc + 1) & 1].f);
                issue_sc0(lor + (kc + 1) * 512, pfl[(kc + 1) & 1].f);
                asm volatile("s_waitcnt vmcnt(2)" ::: "memory");
            } else {
                asm volatile("s_waitcnt vmcnt(0)" ::: "memory");
            }
            __builtin_amdgcn_sched_barrier(0);

            const v16u ha = pfh[kc & 1];
            const v16u la = pfl[kc & 1];

            // d partial: h = bf2f(hi) + bf2f(lo), two elems per u32
            {
                const float* wf = &wfc_s[kc * 32 + l4 * 8];
                unsigned int uu[4] = {ha.u.x, ha.u.y, ha.u.z, ha.u.w};
                unsigned int ll[4] = {la.u.x, la.u.y, la.u.z, la.u.w};
                #pragma unroll
                for (int i = 0; i < 4; ++i) {
                    float h0 = __uint_as_float(uu[i] << 16)
                             + __uint_as_float(ll[i] << 16);
                    float h1 = __uint_as_float(uu[i] & 0xffff0000u)
                             + __uint_as_float(ll[i] & 0xffff0000u);
                    dsum = fmaf(h0, wf[2 * i + 0], dsum);
                    dsum = fmaf(h1, wf[2 * i + 1], dsum);
                }
            }

            #pragma unroll
            for (int nt = 0; nt < 8; ++nt) {
                short8 bhi = *(const short8*)&whi_s[(nt * 8 + kc) * 512 + lane * 8];
                short8 blo = *(const short8*)&wlo_s[(nt * 8 + kc) * 512 + lane * 8];
                acc[nt] = __builtin_amdgcn_mfma_f32_16x16x32_bf16(ha.s, bhi, acc[nt], 0, 0, 0);
                acc[nt] = __builtin_amdgcn_mfma_f32_16x16x32_bf16(la.s, bhi, acc[nt], 0, 0, 0);
                acc[nt] = __builtin_amdgcn_mfma_f32_16x16x32_bf16(ha.s, blo, acc[nt], 0, 0, 0);
            }
        }

        // d(t-1) = h(t)·wfc + bfc  (reduce over the 4 l4 groups)
        dsum += __shfl_xor(dsum, 16);
        dsum += __shfl_xor(dsum, 32);
        float d = dsum + bfc;
        if (p == 0 && lane < 16)
            out[(size_t)(bbase + mtc * 16 + lane) * TLEN + (t - 1)] = d;
        float dreg[4];
        #pragma unroll
        for (int r = 0; r < 4; ++r) dreg[r] = __shfl(d, l4 * 4 + r);

        // cell update + h(t+1) split store
        unsigned short* hiw = cbase + (((t + 1) & 1) * 2 + 0) * PLANE2;
        unsigned short* low = cbase + (((t + 1) & 1) * 2 + 1) * PLANE2;
        #pragma unroll
        for (int half = 0; half < 2; ++half) {
            #pragma unroll
            for (int r = 0; r < 4; ++r) {
                float gi = acc[0 + half][r] + fmaf(dreg[r], wihv[0 + half], biasv[0 + half]);
                float gf = acc[2 + half][r] + fmaf(dreg[r], wihv[2 + half], biasv[2 + half]);
                float gg = acc[4 + half][r] + fmaf(dreg[r], wihv[4 + half], biasv[4 + half]);
                float go = acc[6 + half][r] + fmaf(dreg[r], wihv[6 + half], biasv[6 + half]);
                float c = fmaf(sigf(gf), c_r[half][r], sigf(gi) * tanhf_fast(gg));
                c_r[half][r] = c;
                float h = sigf(go) * tanhf_fast(c);
                int lane_d = l4 * 4 + r + 16 * (half * 2 + (l15 >> 3));
                int idx = (mtc * 8 + p) * 512 + lane_d * 8 + (l15 & 7);
                unsigned int u = __float_as_uint(h);
                hiw[idx] = (unsigned short)(u >> 16);
                float res = h - __uint_as_float(u & 0xffff0000u);
                low[idx] = f2bf_rne(res);
            }
        }
        asm volatile("s_waitcnt vmcnt(0)" ::: "memory");   // own stores drained
        if (lane == 0) atomicAdd(&cnt[cohort], 1u);
        if (mtc == 0 && lane == 0) {
            int guard = 0;
            while (__hip_atomic_load(&cnt[cohort], __ATOMIC_RELAXED,
                                     __HIP_MEMORY_SCOPE_WORKGROUP) < 8u * (unsigned)(t + 1)) {
                if (++guard > (1 << 20)) break;
            }
            __hip_atomic_store(&flgc[p], (unsigned int)(t + 1),
                               __ATOMIC_RELEASE, __HIP_MEMORY_SCOPE_AGENT);
        }
    }

    // ================= epilogue: out[:,511] = h(512)·wfc + bfc =================
    {
        int guard = 0;
        for (;;) {
            unsigned int v = __hip_atomic_load(&flgc[lane & 7], __ATOMIC_RELAXED,
                                               __HIP_MEMORY_SCOPE_AGENT);
            if (__all(v >= (unsigned int)TLEN)) break;
            if (++guard > (1 << 20)) break;
        }
        if (p == 0) {
            const unsigned short* hir = cbase + 0 * PLANE2 + (mtc * 8) * 512 + lane * 8;
            const unsigned short* lor = cbase + 1 * PLANE2 + (mtc * 8) * 512 + lane * 8;
            float dsum = 0.0f;
            #pragma unroll
            for (int kc = 0; kc < 8; ++kc) {
                v16u va, vb;
                issue_sc0(hir + kc * 512, va.f);
                issue_sc0(lor + kc * 512, vb.f);
                asm volatile("s_waitcnt vmcnt(0)" ::: "memory");
                __builtin_amdgcn_sched_barrier(0);
                const float* wf = &wfc_s[kc * 32 + l4 * 8];
                unsigned int uu[4] = {va.u.x, va.u.y, va.u.z, va.u.w};
                unsigned int ll[4] = {vb.u.x, vb.u.y, vb.u.z, vb.u.w};
                #pragma unroll
                for (int i = 0; i < 4; ++i) {
                    float h0 = __uint_as_float(uu[i] << 16)
                             + __uint_as_float(ll[i] << 16);
                    float h1 = __uint_as_float(uu[i] & 0xffff0000u)
                             + __uint_as_float(ll[i] & 0xffff0000u);
                    dsum = fmaf(h0, wf[2 * i + 0], dsum);
                    dsum = fmaf(h1, wf[2 * i + 1], dsum);
                }
            }
            dsum += __shfl_xor(dsum, 16);
            dsum += __shfl_xor(dsum, 32);
            if (lane < 16)
                out[(size_t)(bbase + mtc * 16 + lane) * TLEN + (TLEN - 1)] = dsum + bfc;
        }
    }
}

// ================= fallback (r8 kernel, needs no workspace) =================
#define BB 32
__global__ __launch_bounds__(NTHR, 4) void lstm_mfma7(
    const float* __restrict__ x, const float* __restrict__ W_ih,
    const float* __restrict__ W_hh, const float* __restrict__ b_ih,
    const float* __restrict__ b_hh, const float* __restrict__ W_fc,
    const float* __restrict__ b_fc, float* __restrict__ out)
{
    const int tid = threadIdx.x;
    const int wave = tid >> 6;
    const int lane = tid & 63;
    const int l15 = lane & 15;
    const int l4 = lane >> 4;
    const int bbase = blockIdx.x * BB;

    __shared__ unsigned short hhi[2][16 * 512];
    __shared__ unsigned short hlo[2][16 * 512];
    __shared__ float dpart[16][BB];
    __shared__ float inp_s[BB];

    for (int i = tid; i < 16 * 512; i += NTHR) { hhi[0][i] = 0; hlo[0][i] = 0; }
    if (tid < BB) inp_s[tid] = x[bbase + tid];

    float biasv[4], wihv[4];
    #pragma unroll
    for (int q = 0; q < 4; ++q) {
        int gg = 256 * q + 16 * wave + l15;
        biasv[q] = b_ih[gg] + b_hh[gg];
        wihv[q] = W_ih[gg];
    }
    const float wfc = W_fc[16 * wave + l15];
    const float bfc = b_fc[0];
    const float* __restrict__ wrow = W_hh + (size_t)(16 * wave + l15) * HID + l4 * 8;
    const int kc_w = wave >> 1;
    const int kwhi = (wave & 1) * 2 + (l15 >> 3);
    const int elemw = l15 & 7;

    float c_r[2][4];
    #pragma unroll
    for (int m = 0; m < 2; ++m)
        #pragma unroll
        for (int r = 0; r < 4; ++r) c_r[m][r] = 0.0f;
    __syncthreads();

    #pragma unroll 1
    for (int t = 0; t < TLEN; ++t) {
        const int p = t & 1;
        f32x4 acc[2][4];
        {
            float dv[2][4];
            #pragma unroll
            for (int m = 0; m < 2; ++m)
                #pragma unroll
                for (int r = 0; r < 4; ++r) dv[m][r] = inp_s[16 * m + 4 * l4 + r];
            #pragma unroll
            for (int m = 0; m < 2; ++m)
                #pragma unroll
                for (int q = 0; q < 4; ++q)
                    #pragma unroll
                    for (int r = 0; r < 4; ++r)
                        acc[m][q][r] = fmaf(dv[m][r], wihv[q], biasv[q]);
        }
        #pragma unroll
        for (int kc = 0; kc < 8; ++kc) {
            short8 ahi[2], alo[2];
            #pragma unroll
            for (int m = 0; m < 2; ++m) {
                int aoff = (m * 8 + kc) * 512 + lane * 8;
                ahi[m] = *(const short8*)&hhi[p][aoff];
                alo[m] = *(const short8*)&hlo[p][aoff];
            }
            #pragma unroll
            for (int q = 0; q < 4; ++q) {
                const float* src = wrow + (size_t)q * 256 * HID + kc * 32;
                float4 wa = *(const float4*)src;
                float4 wb = *(const float4*)(src + 4);
                float ff[8] = {wa.x, wa.y, wa.z, wa.w, wb.x, wb.y, wb.z, wb.w};
                short8 bhi, blo;
                #pragma unroll
                for (int e = 0; e < 8; ++e) {
                    unsigned int u = __float_as_uint(ff[e]);
                    bhi[e] = (short)(u >> 16);
                    float res = ff[e] - __uint_as_float(u & 0xffff0000u);
                    blo[e] = (short)(__float_as_uint(res) >> 16);
                }
                #pragma unroll
                for (int m = 0; m < 2; ++m) {
                    acc[m][q] = __builtin_amdgcn_mfma_f32_16x16x32_bf16(ahi[m], bhi, acc[m][q], 0, 0, 0);
                    acc[m][q] = __builtin_amdgcn_mfma_f32_16x16x32_bf16(alo[m], bhi, acc[m][q], 0, 0, 0);
                    acc[m][q] = __builtin_amdgcn_mfma_f32_16x16x32_bf16(ahi[m], blo, acc[m][q], 0, 0, 0);
                }
            }
        }
        #pragma unroll
        for (int m = 0; m < 2; ++m) {
            #pragma unroll
            for (int r = 0; r < 4; ++r) {
                float gi = acc[m][0][r];
                float gf = acc[m][1][r];
                float gg = acc[m][2][r];
                float go = acc[m][3][r];
                float c = fmaf(sigf(gf), c_r[m][r], sigf(gi) * tanhf_fast(gg));
                c_r[m][r] = c;
                float h = sigf(go) * tanhf_fast(c);
                unsigned short hh = f2bf_rne(h);
                float hres = h - bf2f(hh);
                int haddr = (m * 8 + kc_w) * 512 + ((4 * l4 + r) + 16 * kwhi) * 8 + elemw;
                hhi[p ^ 1][haddr] = hh;
                hlo[p ^ 1][haddr] = f2bf_rne(hres);
                float s = h * wfc;
                s += __shfl_xor(s, 1);
                s += __shfl_xor(s, 2);
                s += __shfl_xor(s, 4);
                s += __shfl_xor(s, 8);
                if (l15 == 0) dpart[wave][16 * m + 4 * l4 + r] = s;
            }
        }
        __syncthreads();
        if (tid < BB) {
            float s = bfc;
            #pragma unroll
            for (int w = 0; w < 16; ++w) s += dpart[w][tid];
            inp_s[tid] = s;
            out[(size_t)(bbase + tid) * TLEN + t] = s;
        }
        __syncthreads();
    }
}

extern "C" void kernel_launch(void* const* d_in, const int* in_sizes, int n_in,
                              void* d_out, int out_size, void* d_ws, size_t ws_size,
                              hipStream_t stream) {
    const float* x    = (const float*)d_in[0];
    const float* W_ih = (const float*)d_in[1];
    const float* W_hh = (const float*)d_in[2];
    const float* b_ih = (const float*)d_in[3];
    const float* b_hh = (const float*)d_in[4];
    const float* W_fc = (const float*)d_in[5];
    const float* b_fc = (const float*)d_in[6];
    float* out = (float*)d_out;

    const int BATCH = in_sizes[0];   // 8192

    if (ws_size >= WS_NEEDED) {
        unsigned int* flags = (unsigned int*)((char*)d_ws + FLAGS_OFF);
        hipMemsetAsync(flags, 0, (size_t)NGRP * 2 * FLAGSET * 4, stream);
        lstm_coop3<<<BATCH / BBG * GSIZE, NTHR, 0, stream>>>(
            x, W_ih, W_hh, b_ih, b_hh, W_fc, b_fc,
            (unsigned short*)d_ws, flags, out);
    } else {
        lstm_mfma7<<<BATCH / BB, NTHR, 0, stream>>>(
            x, W_ih, W_hh, b_ih, b_hh, W_fc, b_fc, out);
    }
}

// Round 12
// 11251.272 us; speedup vs baseline: 1.4176x; 1.4176x over previous
//
#include <hip/hip_runtime.h>
#include <math.h>

#define HID   256
#define TLEN  512
#define NTHR  1024
#define GSIZE 8
#define NGRP  32
#define BBG   256            // batches per group

// h exchange: [NGRP][2 bufs][2 sel(hi,lo)][65536 u16]  (A-fragment order)
#define PLANE_U16 (16 * 8 * 512)                        // 65536 u16 = 128 KiB
#define HEX_U16   ((size_t)NGRP * 2 * 2 * PLANE_U16)    // 8M u16 = 16 MiB
#define FLAGS_OFF (HEX_U16 * 2)                         // bytes (== r10 layout)
#define WS_NEEDED (FLAGS_OFF + (size_t)NGRP * GSIZE * 4)

typedef __attribute__((ext_vector_type(8))) short short8;
typedef __attribute__((ext_vector_type(4))) float f32x4;

typedef union {
    float4 f;
    uint4  u;
    short8 s;
} v16u;

static __device__ __forceinline__ unsigned short f2bf_rne(float x) {
    unsigned int u = __float_as_uint(x);
    unsigned int r = (u + 0x7FFFu + ((u >> 16) & 1u)) >> 16;
    return (unsigned short)r;
}
static __device__ __forceinline__ float bf2f(unsigned short h) {
    return __uint_as_float(((unsigned int)h) << 16);
}
static __device__ __forceinline__ float sigf(float x) {
    return 1.0f / (1.0f + __expf(-x));
}
static __device__ __forceinline__ float tanhf_fast(float x) {
    return 1.0f - 2.0f / (1.0f + __expf(2.0f * x));
}

// one dwordx4 load, L1-bypass (sc0), no wait — caller waits via vmcnt
static __device__ __forceinline__ void issue_sc0(const void* p, float4& a) {
    asm volatile("global_load_dwordx4 %0, %1, off sc0"
                 : "=&v"(a) : "v"(p) : "memory");
}

// ======= cooperative weight-stationary, 8x2 register-blocked wave grid =======
__global__ __launch_bounds__(NTHR, 4) void lstm_coop5(
    const float* __restrict__ x,
    const float* __restrict__ W_ih,
    const float* __restrict__ W_hh,
    const float* __restrict__ b_ih,
    const float* __restrict__ b_hh,
    const float* __restrict__ W_fc,
    const float* __restrict__ b_fc,
    unsigned short* __restrict__ hexw,  // ws: split-bf16 h exchange planes
    unsigned int* __restrict__ flags,   // ws: [NGRP][GSIZE], memset 0 per launch
    float* __restrict__ out)
{
    const int tid  = threadIdx.x;
    const int bid  = blockIdx.x;
    const int xcd  = bid & 7;          // round-robin XCD mapping
    const int p    = (bid >> 3) & 7;   // producer index within group
    const int gsub = bid >> 6;         // 0..3
    const int g    = xcd * 4 + gsub;   // group 0..31 (XCD-local)
    const int bbase = g * BBG;
    const int wv   = tid >> 6;         // 0..15
    const int lane = tid & 63;
    const int l15  = lane & 15;
    const int l4   = lane >> 4;
    const int wrow = wv >> 1;          // 0..7 : M-row (owns mt_g = wrow*2 + {0,1})
    const int half = wv & 1;           // N-col : owns units half*16 + l15

    __shared__ unsigned short whi_s[64 * 512];  // 64 KiB  B-frags hi
    __shared__ unsigned short wlo_s[64 * 512];  // 64 KiB  B-frags lo
    __shared__ float wfc_s[HID];

    // ---- stage this block's 128 gate-rows into LDS (split bf16, B-frag order) ----
    #pragma unroll
    for (int i = 0; i < 4; ++i) {
        int tile = wv * 4 + i;            // 0..63 = nt*8 + kc
        int nt = tile >> 3, kc = tile & 7;
        int q = nt >> 1, hf = nt & 1;
        int grow = q * 256 + p * 32 + hf * 16 + l15;
        int k0 = kc * 32 + l4 * 8;
        const float* src = W_hh + (size_t)grow * HID + k0;
        float4 wa = *(const float4*)src;
        float4 wb = *(const float4*)(src + 4);
        float ff[8] = {wa.x, wa.y, wa.z, wa.w, wb.x, wb.y, wb.z, wb.w};
        short8 hi8, lo8;
        #pragma unroll
        for (int e = 0; e < 8; ++e) {
            unsigned int u = __float_as_uint(ff[e]);
            hi8[e] = (short)(u >> 16);
            float res = ff[e] - __uint_as_float(u & 0xffff0000u);
            lo8[e] = (short)f2bf_rne(res);
        }
        *(short8*)&whi_s[tile * 512 + lane * 8] = hi8;
        *(short8*)&wlo_s[tile * 512 + lane * 8] = lo8;
    }
    if (tid < HID) wfc_s[tid] = W_fc[tid];

    // per-lane gate constants: unit u = p*32 + half*16 + l15, gate rows q*256+u
    float biasv[4], wihv[4];
    #pragma unroll
    for (int q = 0; q < 4; ++q) {
        int grow = q * 256 + p * 32 + half * 16 + l15;
        biasv[q] = b_ih[grow] + b_hh[grow];
        wihv[q]  = W_ih[grow];
    }
    const float bfc = b_fc[0];

    float c_r[2][4];
    #pragma unroll
    for (int mt = 0; mt < 2; ++mt)
        #pragma unroll
        for (int r = 0; r < 4; ++r) c_r[mt][r] = 0.0f;

    unsigned int* flg = flags + g * GSIZE;
    unsigned short* const gbase = hexw + (size_t)g * 4 * PLANE_U16;
    // plane(buf,sel) = gbase + (buf*2+sel)*PLANE_U16

    // h-store index (step-invariant parts): value (mt,r) -> batch b=(wrow*2+mt)*16+l4*4+r
    //   idx = ((wrow*2+mt)*8 + p)*512 + (b&15 + 16*(half*2 + (l15>>3)))*8 + (l15&7)
    const int stbase = 16 * (half * 2 + (l15 >> 3)) * 8 + (l15 & 7);

    __syncthreads();

    // ================= step 0: gates = bias + x*wih (h=0) =================
    {
        unsigned short* hiw = gbase + (1 * 2 + 0) * PLANE_U16;  // h(1) -> buf 1
        unsigned short* low = gbase + (1 * 2 + 1) * PLANE_U16;
        #pragma unroll
        for (int mt = 0; mt < 2; ++mt) {
            #pragma unroll
            for (int r = 0; r < 4; ++r) {
                float dv = x[bbase + (wrow * 2 + mt) * 16 + l4 * 4 + r];
                float gi = fmaf(dv, wihv[0], biasv[0]);
                float gf = fmaf(dv, wihv[1], biasv[1]);
                float gg = fmaf(dv, wihv[2], biasv[2]);
                float go = fmaf(dv, wihv[3], biasv[3]);
                float c = fmaf(sigf(gf), c_r[mt][r], sigf(gi) * tanhf_fast(gg));
                c_r[mt][r] = c;
                float h = sigf(go) * tanhf_fast(c);
                int idx = ((wrow * 2 + mt) * 8 + p) * 512 + (l4 * 4 + r) * 8 + stbase;
                unsigned int u = __float_as_uint(h);
                hiw[idx] = (unsigned short)(u >> 16);
                float res = h - __uint_as_float(u & 0xffff0000u);
                low[idx] = f2bf_rne(res);
            }
        }
        asm volatile("s_waitcnt vmcnt(0)" ::: "memory");
        __syncthreads();
        if (tid == 0)
            __hip_atomic_store(&flg[p], 1u, __ATOMIC_RELEASE, __HIP_MEMORY_SCOPE_AGENT);
    }

    // ================= steps 1..511 =================
    #pragma unroll 1
    for (int t = 1; t < TLEN; ++t) {
        // wait for all 8 shares of h(t) — one wave polls, block barrier releases
        if (tid < GSIZE) {
            int guard = 0;
            while (__hip_atomic_load(&flg[tid], __ATOMIC_RELAXED, __HIP_MEMORY_SCOPE_AGENT)
                       < (unsigned int)t) {
                if (++guard > (1 << 20)) break;   // failsafe: never hang
            }
        }
        __syncthreads();

        const unsigned short* hir = gbase + ((t & 1) * 2 + 0) * PLANE_U16 + lane * 8;
        const unsigned short* lor = gbase + ((t & 1) * 2 + 1) * PLANE_U16 + lane * 8;

        f32x4 acc[2][4];
        #pragma unroll
        for (int mt = 0; mt < 2; ++mt)
            #pragma unroll
            for (int q = 0; q < 4; ++q)
                #pragma unroll
                for (int r = 0; r < 4; ++r) acc[mt][q][r] = 0.0f;

        float dsum[2] = {0.0f, 0.0f};
        v16u pfh[2][2], pfl[2][2];
        #pragma unroll
        for (int mt = 0; mt < 2; ++mt) {
            int aoff = ((wrow * 2 + mt) * 8 + 0) * 512;
            issue_sc0(hir + aoff, pfh[0][mt].f);
            issue_sc0(lor + aoff, pfl[0][mt].f);
        }

        #pragma unroll
        for (int kc = 0; kc < 8; ++kc) {
            if (kc < 7) {
                #pragma unroll
                for (int mt = 0; mt < 2; ++mt) {
                    int aoff = ((wrow * 2 + mt) * 8 + (kc + 1)) * 512;
                    issue_sc0(hir + aoff, pfh[(kc + 1) & 1][mt].f);
                    issue_sc0(lor + aoff, pfl[(kc + 1) & 1][mt].f);
                }
                asm volatile("s_waitcnt vmcnt(4)" ::: "memory");
            } else {
                asm volatile("s_waitcnt vmcnt(0)" ::: "memory");
            }
            __builtin_amdgcn_sched_barrier(0);

            // d partials: h = bf2f(hi)+bf2f(lo), two elems per u32
            {
                const float* wf = &wfc_s[kc * 32 + l4 * 8];
                #pragma unroll
                for (int mt = 0; mt < 2; ++mt) {
                    unsigned int uu[4] = {pfh[kc & 1][mt].u.x, pfh[kc & 1][mt].u.y,
                                          pfh[kc & 1][mt].u.z, pfh[kc & 1][mt].u.w};
                    unsigned int ll[4] = {pfl[kc & 1][mt].u.x, pfl[kc & 1][mt].u.y,
                                          pfl[kc & 1][mt].u.z, pfl[kc & 1][mt].u.w};
                    #pragma unroll
                    for (int i = 0; i < 4; ++i) {
                        float h0 = __uint_as_float(uu[i] << 16)
                                 + __uint_as_float(ll[i] << 16);
                        float h1 = __uint_as_float(uu[i] & 0xffff0000u)
                                 + __uint_as_float(ll[i] & 0xffff0000u);
                        dsum[mt] = fmaf(h0, wf[2 * i + 0], dsum[mt]);
                        dsum[mt] = fmaf(h1, wf[2 * i + 1], dsum[mt]);
                    }
                }
            }

            // MFMA: 4 gate-quads (nt = q*2+half) x 2 M-tiles x 3 terms
            #pragma unroll
            for (int q = 0; q < 4; ++q) {
                int tile = (q * 2 + half) * 8 + kc;
                short8 bhi = *(const short8*)&whi_s[tile * 512 + lane * 8];
                short8 blo = *(const short8*)&wlo_s[tile * 512 + lane * 8];
                #pragma unroll
                for (int mt = 0; mt < 2; ++mt) {
                    acc[mt][q] = __builtin_amdgcn_mfma_f32_16x16x32_bf16(pfh[kc & 1][mt].s, bhi, acc[mt][q], 0, 0, 0);
                    acc[mt][q] = __builtin_amdgcn_mfma_f32_16x16x32_bf16(pfl[kc & 1][mt].s, bhi, acc[mt][q], 0, 0, 0);
                    acc[mt][q] = __builtin_amdgcn_mfma_f32_16x16x32_bf16(pfh[kc & 1][mt].s, blo, acc[mt][q], 0, 0, 0);
                }
            }
        }

        // d(t-1) = h(t)·wfc + bfc  (reduce over the 4 l4 groups)
        float d[2];
        #pragma unroll
        for (int mt = 0; mt < 2; ++mt) {
            float s = dsum[mt];
            s += __shfl_xor(s, 16);
            s += __shfl_xor(s, 32);
            d[mt] = s + bfc;
        }
        if (p == 0 && half == 0 && l4 == 0) {
            #pragma unroll
            for (int mt = 0; mt < 2; ++mt)
                out[(size_t)(bbase + (wrow * 2 + mt) * 16 + l15) * TLEN + (t - 1)] = d[mt];
        }

        // cell update + h(t+1) split store
        unsigned short* hiw = gbase + (((t + 1) & 1) * 2 + 0) * PLANE_U16;
        unsigned short* low = gbase + (((t + 1) & 1) * 2 + 1) * PLANE_U16;
        #pragma unroll
        for (int mt = 0; mt < 2; ++mt) {
            #pragma unroll
            for (int r = 0; r < 4; ++r) {
                float dv = __shfl(d[mt], l4 * 4 + r);
                float gi = acc[mt][0][r] + fmaf(dv, wihv[0], biasv[0]);
                float gf = acc[mt][1][r] + fmaf(dv, wihv[1], biasv[1]);
                float gg = acc[mt][2][r] + fmaf(dv, wihv[2], biasv[2]);
                float go = acc[mt][3][r] + fmaf(dv, wihv[3], biasv[3]);
                float c = fmaf(sigf(gf), c_r[mt][r], sigf(gi) * tanhf_fast(gg));
                c_r[mt][r] = c;
                float h = sigf(go) * tanhf_fast(c);
                int idx = ((wrow * 2 + mt) * 8 + p) * 512 + (l4 * 4 + r) * 8 + stbase;
                unsigned int u = __float_as_uint(h);
                hiw[idx] = (unsigned short)(u >> 16);
                float res = h - __uint_as_float(u & 0xffff0000u);
                low[idx] = f2bf_rne(res);
            }
        }
        asm volatile("s_waitcnt vmcnt(0)" ::: "memory");   // drain stores
        __syncthreads();
        if (tid == 0)
            __hip_atomic_store(&flg[p], (unsigned int)(t + 1),
                               __ATOMIC_RELEASE, __HIP_MEMORY_SCOPE_AGENT);
    }

    // ================= epilogue: out[:,511] = h(512)·wfc + bfc =================
    {
        if (tid < GSIZE) {
            int guard = 0;
            while (__hip_atomic_load(&flg[tid], __ATOMIC_RELAXED, __HIP_MEMORY_SCOPE_AGENT)
                       < (unsigned int)TLEN) {
                if (++guard > (1 << 20)) break;
            }
        }
        __syncthreads();
        if (p == 0) {
            const unsigned short* hir = gbase + 0 * PLANE_U16 + lane * 8;
            const unsigned short* lor = gbase + 1 * PLANE_U16 + lane * 8;
            float dsum[2] = {0.0f, 0.0f};
            #pragma unroll
            for (int kc = 0; kc < 8; ++kc) {
                #pragma unroll
                for (int mt = 0; mt < 2; ++mt) {
                    v16u va, vb;
                    int aoff = ((wrow * 2 + mt) * 8 + kc) * 512;
                    issue_sc0(hir + aoff, va.f);
                    issue_sc0(lor + aoff, vb.f);
                    asm volatile("s_waitcnt vmcnt(0)" ::: "memory");
                    __builtin_amdgcn_sched_barrier(0);
                    const float* wf = &wfc_s[kc * 32 + l4 * 8];
                    unsigned int uu[4] = {va.u.x, va.u.y, va.u.z, va.u.w};
                    unsigned int ll[4] = {vb.u.x, vb.u.y, vb.u.z, vb.u.w};
                    #pragma unroll
                    for (int i = 0; i < 4; ++i) {
                        float h0 = __uint_as_float(uu[i] << 16)
                                 + __uint_as_float(ll[i] << 16);
                        float h1 = __uint_as_float(uu[i] & 0xffff0000u)
                                 + __uint_as_float(ll[i] & 0xffff0000u);
                        dsum[mt] = fmaf(h0, wf[2 * i + 0], dsum[mt]);
                        dsum[mt] = fmaf(h1, wf[2 * i + 1], dsum[mt]);
                    }
                }
            }
            #pragma unroll
            for (int mt = 0; mt < 2; ++mt) {
                float s = dsum[mt];
                s += __shfl_xor(s, 16);
                s += __shfl_xor(s, 32);
                if (half == 0 && l4 == 0)
                    out[(size_t)(bbase + (wrow * 2 + mt) * 16 + l15) * TLEN + (TLEN - 1)] = s + bfc;
            }
        }
    }
}

// ================= fallback (r8 kernel, needs no workspace) =================
#define BB 32
__global__ __launch_bounds__(NTHR, 4) void lstm_mfma7(
    const float* __restrict__ x, const float* __restrict__ W_ih,
    const float* __restrict__ W_hh, const float* __restrict__ b_ih,
    const float* __restrict__ b_hh, const float* __restrict__ W_fc,
    const float* __restrict__ b_fc, float* __restrict__ out)
{
    const int tid = threadIdx.x;
    const int wave = tid >> 6;
    const int lane = tid & 63;
    const int l15 = lane & 15;
    const int l4 = lane >> 4;
    const int bbase = blockIdx.x * BB;

    __shared__ unsigned short hhi[2][16 * 512];
    __shared__ unsigned short hlo[2][16 * 512];
    __shared__ float dpart[16][BB];
    __shared__ float inp_s[BB];

    for (int i = tid; i < 16 * 512; i += NTHR) { hhi[0][i] = 0; hlo[0][i] = 0; }
    if (tid < BB) inp_s[tid] = x[bbase + tid];

    float biasv[4], wihv[4];
    #pragma unroll
    for (int q = 0; q < 4; ++q) {
        int gg = 256 * q + 16 * wave + l15;
        biasv[q] = b_ih[gg] + b_hh[gg];
        wihv[q] = W_ih[gg];
    }
    const float wfc = W_fc[16 * wave + l15];
    const float bfc = b_fc[0];
    const float* __restrict__ wrow = W_hh + (size_t)(16 * wave + l15) * HID + l4 * 8;
    const int kc_w = wave >> 1;
    const int kwhi = (wave & 1) * 2 + (l15 >> 3);
    const int elemw = l15 & 7;

    float c_r[2][4];
    #pragma unroll
    for (int m = 0; m < 2; ++m)
        #pragma unroll
        for (int r = 0; r < 4; ++r) c_r[m][r] = 0.0f;
    __syncthreads();

    #pragma unroll 1
    for (int t = 0; t < TLEN; ++t) {
        const int p = t & 1;
        f32x4 acc[2][4];
        {
            float dv[2][4];
            #pragma unroll
            for (int m = 0; m < 2; ++m)
                #pragma unroll
                for (int r = 0; r < 4; ++r) dv[m][r] = inp_s[16 * m + 4 * l4 + r];
            #pragma unroll
            for (int m = 0; m < 2; ++m)
                #pragma unroll
                for (int q = 0; q < 4; ++q)
                    #pragma unroll
                    for (int r = 0; r < 4; ++r)
                        acc[m][q][r] = fmaf(dv[m][r], wihv[q], biasv[q]);
        }
        #pragma unroll
        for (int kc = 0; kc < 8; ++kc) {
            short8 ahi[2], alo[2];
            #pragma unroll
            for (int m = 0; m < 2; ++m) {
                int aoff = (m * 8 + kc) * 512 + lane * 8;
                ahi[m] = *(const short8*)&hhi[p][aoff];
                alo[m] = *(const short8*)&hlo[p][aoff];
            }
            #pragma unroll
            for (int q = 0; q < 4; ++q) {
                const float* src = wrow + (size_t)q * 256 * HID + kc * 32;
                float4 wa = *(const float4*)src;
                float4 wb = *(const float4*)(src + 4);
                float ff[8] = {wa.x, wa.y, wa.z, wa.w, wb.x, wb.y, wb.z, wb.w};
                short8 bhi, blo;
                #pragma unroll
                for (int e = 0; e < 8; ++e) {
                    unsigned int u = __float_as_uint(ff[e]);
                    bhi[e] = (short)(u >> 16);
                    float res = ff[e] - __uint_as_float(u & 0xffff0000u);
                    blo[e] = (short)(__float_as_uint(res) >> 16);
                }
                #pragma unroll
                for (int m = 0; m < 2; ++m) {
                    acc[m][q] = __builtin_amdgcn_mfma_f32_16x16x32_bf16(ahi[m], bhi, acc[m][q], 0, 0, 0);
                    acc[m][q] = __builtin_amdgcn_mfma_f32_16x16x32_bf16(alo[m], bhi, acc[m][q], 0, 0, 0);
                    acc[m][q] = __builtin_amdgcn_mfma_f32_16x16x32_bf16(ahi[m], blo, acc[m][q], 0, 0, 0);
                }
            }
        }
        #pragma unroll
        for (int m = 0; m < 2; ++m) {
            #pragma unroll
            for (int r = 0; r < 4; ++r) {
                float gi = acc[m][0][r];
                float gf = acc[m][1][r];
                float gg = acc[m][2][r];
                float go = acc[m][3][r];
                float c = fmaf(sigf(gf), c_r[m][r], sigf(gi) * tanhf_fast(gg));
                c_r[m][r] = c;
                float h = sigf(go) * tanhf_fast(c);
                unsigned short hh = f2bf_rne(h);
                float hres = h - bf2f(hh);
                int haddr = (m * 8 + kc_w) * 512 + ((4 * l4 + r) + 16 * kwhi) * 8 + elemw;
                hhi[p ^ 1][haddr] = hh;
                hlo[p ^ 1][haddr] = f2bf_rne(hres);
                float s = h * wfc;
                s += __shfl_xor(s, 1);
                s += __shfl_xor(s, 2);
                s += __shfl_xor(s, 4);
                s += __shfl_xor(s, 8);
                if (l15 == 0) dpart[wave][16 * m + 4 * l4 + r] = s;
            }
        }
        __syncthreads();
        if (tid < BB) {
            float s = bfc;
            #pragma unroll
            for (int w = 0; w < 16; ++w) s += dpart[w][tid];
            inp_s[tid] = s;
            out[(size_t)(bbase + tid) * TLEN + t] = s;
        }
        __syncthreads();
    }
}

extern "C" void kernel_launch(void* const* d_in, const int* in_sizes, int n_in,
                              void* d_out, int out_size, void* d_ws, size_t ws_size,
                              hipStream_t stream) {
    const float* x    = (const float*)d_in[0];
    const float* W_ih = (const float*)d_in[1];
    const float* W_hh = (const float*)d_in[2];
    const float* b_ih = (const float*)d_in[3];
    const float* b_hh = (const float*)d_in[4];
    const float* W_fc = (const float*)d_in[5];
    const float* b_fc = (const float*)d_in[6];
    float* out = (float*)d_out;

    const int BATCH = in_sizes[0];   // 8192

    if (ws_size >= WS_NEEDED) {
        unsigned int* flags = (unsigned int*)((char*)d_ws + FLAGS_OFF);
        hipMemsetAsync(flags, 0, (size_t)NGRP * GSIZE * 4, stream);
        lstm_coop5<<<BATCH / BBG * GSIZE, NTHR, 0, stream>>>(
            x, W_ih, W_hh, b_ih, b_hh, W_fc, b_fc,
            (unsigned short*)d_ws, flags, out);
    } else {
        lstm_mfma7<<<BATCH / BB, NTHR, 0, stream>>>(
            x, W_ih, W_hh, b_ih, b_hh, W_fc, b_fc, out);
    }
}

// Round 14
// 8292.826 us; speedup vs baseline: 1.9234x; 1.3567x over previous
//
#include <hip/hip_runtime.h>
#include <math.h>

#define HID   256
#define TLEN  512
#define NTHR  1024
#define GSIZE 8
#define NGRP  32
#define BBG   256            // batches per group

// h exchange: [NGRP][2 bufs][2 sel(hi,lo)][65536 u16]  (A-fragment order)
#define PLANE_U16 (16 * 8 * 512)                        // 65536 u16 = 128 KiB
#define HEX_U16   ((size_t)NGRP * 2 * 2 * PLANE_U16)    // 8M u16 = 16 MiB
#define FLAGS_OFF (HEX_U16 * 2)                         // bytes
#define NFLAGS    (NGRP * GSIZE)
#define WS_NEEDED (FLAGS_OFF + (size_t)NFLAGS * 4)

typedef __attribute__((ext_vector_type(8))) short short8;
typedef __attribute__((ext_vector_type(4))) float f32x4;

typedef union {
    float4 f;
    uint4  u;
    short8 s;
} v16u;

static __device__ __forceinline__ unsigned short f2bf_rne(float x) {
    unsigned int u = __float_as_uint(x);
    unsigned int r = (u + 0x7FFFu + ((u >> 16) & 1u)) >> 16;
    return (unsigned short)r;
}
static __device__ __forceinline__ float sigf(float x) {
    return 1.0f / (1.0f + __expf(-x));
}
static __device__ __forceinline__ float tanhf_fast(float x) {
    return 1.0f - 2.0f / (1.0f + __expf(2.0f * x));
}

// ---- device-coherent (MALL-level) memory ops: sc0 sc1 = bypass L1 and L2 ----
static __device__ __forceinline__ void issue_dev(const void* p, float4& a) {
    asm volatile("global_load_dwordx4 %0, %1, off sc0 sc1"
                 : "=&v"(a) : "v"(p) : "memory");
}
static __device__ __forceinline__ void store_short_dev(void* p, unsigned int v) {
    asm volatile("global_store_short %0, %1, off sc0 sc1"
                 :: "v"(p), "v"(v) : "memory");
}
static __device__ __forceinline__ unsigned int load_flag_dev(const unsigned int* p) {
    unsigned int v;
    asm volatile("global_load_dword %0, %1, off sc0 sc1\n\t"
                 "s_waitcnt vmcnt(0)"
                 : "=v"(v) : "v"(p) : "memory");
    return v;
}
static __device__ __forceinline__ void store_flag_dev(unsigned int* p, unsigned int v) {
    asm volatile("global_store_dword %0, %1, off sc0 sc1"
                 :: "v"(p), "v"(v) : "memory");
}

// flags init: device-coherent zeroing (hipMemsetAsync blit stores may not
// reach the MALL before our sc1 polls read it — replay hazard)
__global__ void init_flags(unsigned int* flags) {
    int i = blockIdx.x * 256 + threadIdx.x;
    if (i < NFLAGS) store_flag_dev(flags + i, 0u);
}

// ================= cooperative weight-stationary kernel =================
__global__ __launch_bounds__(NTHR, 4) void lstm_coop7(
    const float* __restrict__ x,
    const float* __restrict__ W_ih,
    const float* __restrict__ W_hh,
    const float* __restrict__ b_ih,
    const float* __restrict__ b_hh,
    const float* __restrict__ W_fc,
    const float* __restrict__ b_fc,
    unsigned short* __restrict__ hexw,  // ws: split-bf16 h exchange planes
    unsigned int* __restrict__ flags,   // ws: [NGRP][GSIZE], init by init_flags
    float* __restrict__ out)
{
    const int tid  = threadIdx.x;
    const int bid  = blockIdx.x;
    const int xcd  = bid & 7;
    const int p    = (bid >> 3) & 7;   // producer index within group
    const int gsub = bid >> 6;         // 0..3
    const int g    = xcd * 4 + gsub;   // group 0..31
    const int bbase = g * BBG;
    const int mt   = tid >> 6;         // wave = M-tile (16 batches)
    const int lane = tid & 63;
    const int l15  = lane & 15;
    const int l4   = lane >> 4;

    __shared__ unsigned short whi_s[64 * 512];  // 64 KiB  B-frags hi
    __shared__ unsigned short wlo_s[64 * 512];  // 64 KiB  B-frags lo
    __shared__ float wfc_s[HID];

    // ---- stage this block's 128 gate-rows into LDS (split bf16, B-frag order) ----
    #pragma unroll
    for (int i = 0; i < 4; ++i) {
        int tile = mt * 4 + i;            // 0..63 = nt*8 + kc
        int nt = tile >> 3, kc = tile & 7;
        int q = nt >> 1, half = nt & 1;
        int grow = q * 256 + p * 32 + half * 16 + l15;
        int k0 = kc * 32 + l4 * 8;
        const float* src = W_hh + (size_t)grow * HID + k0;
        float4 wa = *(const float4*)src;
        float4 wb = *(const float4*)(src + 4);
        float ff[8] = {wa.x, wa.y, wa.z, wa.w, wb.x, wb.y, wb.z, wb.w};
        short8 hi8, lo8;
        #pragma unroll
        for (int e = 0; e < 8; ++e) {
            unsigned int u = __float_as_uint(ff[e]);
            hi8[e] = (short)(u >> 16);
            float res = ff[e] - __uint_as_float(u & 0xffff0000u);
            lo8[e] = (short)f2bf_rne(res);
        }
        *(short8*)&whi_s[tile * 512 + lane * 8] = hi8;
        *(short8*)&wlo_s[tile * 512 + lane * 8] = lo8;
    }
    if (tid < HID) wfc_s[tid] = W_fc[tid];

    // per-lane gate constants: nt = q*2+half -> grow
    float biasv[8], wihv[8];
    #pragma unroll
    for (int nt = 0; nt < 8; ++nt) {
        int grow = (nt >> 1) * 256 + p * 32 + (nt & 1) * 16 + l15;
        biasv[nt] = b_ih[grow] + b_hh[grow];
        wihv[nt]  = W_ih[grow];
    }
    const float bfc = b_fc[0];

    float c_r[2][4];
    #pragma unroll
    for (int half = 0; half < 2; ++half)
        #pragma unroll
        for (int r = 0; r < 4; ++r) c_r[half][r] = 0.0f;

    unsigned int* flg = flags + g * GSIZE;
    unsigned short* const gbase = hexw + (size_t)g * 4 * PLANE_U16;
    // plane(buf,sel) = gbase + (buf*2+sel)*PLANE_U16

    __syncthreads();

    // ================= step 0: gates = bias + x*wih (h=0) =================
    {
        float dreg[4];
        #pragma unroll
        for (int r = 0; r < 4; ++r) dreg[r] = x[bbase + mt * 16 + l4 * 4 + r];

        unsigned short* hiw = gbase + (1 * 2 + 0) * PLANE_U16;  // h(1) -> buf 1
        unsigned short* low = gbase + (1 * 2 + 1) * PLANE_U16;
        #pragma unroll
        for (int half = 0; half < 2; ++half) {
            #pragma unroll
            for (int r = 0; r < 4; ++r) {
                float gi = fmaf(dreg[r], wihv[0 + half], biasv[0 + half]);
                float gf = fmaf(dreg[r], wihv[2 + half], biasv[2 + half]);
                float gg = fmaf(dreg[r], wihv[4 + half], biasv[4 + half]);
                float go = fmaf(dreg[r], wihv[6 + half], biasv[6 + half]);
                float c = fmaf(sigf(gf), c_r[half][r], sigf(gi) * tanhf_fast(gg));
                c_r[half][r] = c;
                float h = sigf(go) * tanhf_fast(c);
                int lane_d = l4 * 4 + r + 16 * (half * 2 + (l15 >> 3));
                int idx = (mt * 8 + p) * 512 + lane_d * 8 + (l15 & 7);
                unsigned int u = __float_as_uint(h);
                store_short_dev(hiw + idx, u >> 16);
                float res = h - __uint_as_float(u & 0xffff0000u);
                store_short_dev(low + idx, (unsigned int)f2bf_rne(res));
            }
        }
        asm volatile("s_waitcnt vmcnt(0)" ::: "memory");   // h at MALL
        __syncthreads();                                   // all waves drained
        if (tid == 0) store_flag_dev(&flg[p], 1u);
    }

    // ================= steps 1..511 =================
    #pragma unroll 1
    for (int t = 1; t < TLEN; ++t) {
        // wait for all 8 shares of h(t)
        if (tid < GSIZE) {
            int guard = 0;
            while (load_flag_dev(&flg[tid]) < (unsigned int)t) {
                if (++guard > (1 << 18)) break;   // failsafe: never hang
            }
        }
        __syncthreads();

        const unsigned short* hir = gbase + ((t & 1) * 2 + 0) * PLANE_U16
                                  + (mt * 8) * 512 + lane * 8;
        const unsigned short* lor = gbase + ((t & 1) * 2 + 1) * PLANE_U16
                                  + (mt * 8) * 512 + lane * 8;

        f32x4 acc[8];
        #pragma unroll
        for (int nt = 0; nt < 8; ++nt)
            #pragma unroll
            for (int r = 0; r < 4; ++r) acc[nt][r] = 0.0f;

        float dsum = 0.0f;
        v16u pfh[3], pfl[3];
        issue_dev(hir, pfh[0].f);
        issue_dev(lor, pfl[0].f);
        issue_dev(hir + 512, pfh[1].f);
        issue_dev(lor + 512, pfl[1].f);

        #pragma unroll
        for (int kc = 0; kc < 8; ++kc) {
            if (kc < 6) {
                issue_dev(hir + (kc + 2) * 512, pfh[(kc + 2) % 3].f);
                issue_dev(lor + (kc + 2) * 512, pfl[(kc + 2) % 3].f);
                asm volatile("s_waitcnt vmcnt(4)" ::: "memory");
            } else if (kc == 6) {
                asm volatile("s_waitcnt vmcnt(2)" ::: "memory");
            } else {
                asm volatile("s_waitcnt vmcnt(0)" ::: "memory");
            }
            __builtin_amdgcn_sched_barrier(0);

            const v16u ha = pfh[kc % 3];
            const v16u la = pfl[kc % 3];

            // d partial: h = bf2f(hi) + bf2f(lo), two elems per u32
            {
                const float* wf = &wfc_s[kc * 32 + l4 * 8];
                unsigned int uu[4] = {ha.u.x, ha.u.y, ha.u.z, ha.u.w};
                unsigned int ll[4] = {la.u.x, la.u.y, la.u.z, la.u.w};
                #pragma unroll
                for (int i = 0; i < 4; ++i) {
                    float h0 = __uint_as_float(uu[i] << 16)
                             + __uint_as_float(ll[i] << 16);
                    float h1 = __uint_as_float(uu[i] & 0xffff0000u)
                             + __uint_as_float(ll[i] & 0xffff0000u);
                    dsum = fmaf(h0, wf[2 * i + 0], dsum);
                    dsum = fmaf(h1, wf[2 * i + 1], dsum);
                }
            }

            #pragma unroll
            for (int nt = 0; nt < 8; ++nt) {
                short8 bhi = *(const short8*)&whi_s[(nt * 8 + kc) * 512 + lane * 8];
                short8 blo = *(const short8*)&wlo_s[(nt * 8 + kc) * 512 + lane * 8];
                acc[nt] = __builtin_amdgcn_mfma_f32_16x16x32_bf16(ha.s, bhi, acc[nt], 0, 0, 0);
                acc[nt] = __builtin_amdgcn_mfma_f32_16x16x32_bf16(la.s, bhi, acc[nt], 0, 0, 0);
                acc[nt] = __builtin_amdgcn_mfma_f32_16x16x32_bf16(ha.s, blo, acc[nt], 0, 0, 0);
            }
        }

        // d(t-1) = h(t)·wfc + bfc  (reduce over the 4 l4 groups)
        dsum += __shfl_xor(dsum, 16);
        dsum += __shfl_xor(dsum, 32);
        float d = dsum + bfc;
        if (p == 0 && lane < 16)
            out[(size_t)(bbase + mt * 16 + lane) * TLEN + (t - 1)] = d;
        float dreg[4];
        #pragma unroll
        for (int r = 0; r < 4; ++r) dreg[r] = __shfl(d, l4 * 4 + r);

        // cell update + h(t+1) split store (device-coherent)
        unsigned short* hiw = gbase + ((((t + 1) & 1)) * 2 + 0) * PLANE_U16;
        unsigned short* low = gbase + ((((t + 1) & 1)) * 2 + 1) * PLANE_U16;
        #pragma unroll
        for (int half = 0; half < 2; ++half) {
            #pragma unroll
            for (int r = 0; r < 4; ++r) {
                float gi = acc[0 + half][r] + fmaf(dreg[r], wihv[0 + half], biasv[0 + half]);
                float gf = acc[2 + half][r] + fmaf(dreg[r], wihv[2 + half], biasv[2 + half]);
                float gg = acc[4 + half][r] + fmaf(dreg[r], wihv[4 + half], biasv[4 + half]);
                float go = acc[6 + half][r] + fmaf(dreg[r], wihv[6 + half], biasv[6 + half]);
                float c = fmaf(sigf(gf), c_r[half][r], sigf(gi) * tanhf_fast(gg));
                c_r[half][r] = c;
                float h = sigf(go) * tanhf_fast(c);
                int lane_d = l4 * 4 + r + 16 * (half * 2 + (l15 >> 3));
                int idx = (mt * 8 + p) * 512 + lane_d * 8 + (l15 & 7);
                unsigned int u = __float_as_uint(h);
                store_short_dev(hiw + idx, u >> 16);
                float res = h - __uint_as_float(u & 0xffff0000u);
                store_short_dev(low + idx, (unsigned int)f2bf_rne(res));
            }
        }
        asm volatile("s_waitcnt vmcnt(0)" ::: "memory");   // h at MALL
        __syncthreads();                                   // all waves drained
        if (tid == 0) store_flag_dev(&flg[p], (unsigned int)(t + 1));
    }

    // ================= epilogue: out[:,511] = h(512)·wfc + bfc =================
    {
        if (tid < GSIZE) {
            int guard = 0;
            while (load_flag_dev(&flg[tid]) < (unsigned int)TLEN) {
                if (++guard > (1 << 18)) break;
            }
        }
        __syncthreads();
        if (p == 0) {
            const unsigned short* hir = gbase + (0 * 2 + 0) * PLANE_U16
                                      + (mt * 8) * 512 + lane * 8;
            const unsigned short* lor = gbase + (0 * 2 + 1) * PLANE_U16
                                      + (mt * 8) * 512 + lane * 8;
            float dsum = 0.0f;
            #pragma unroll
            for (int kc = 0; kc < 8; ++kc) {
                v16u va, vb;
                issue_dev(hir + kc * 512, va.f);
                issue_dev(lor + kc * 512, vb.f);
                asm volatile("s_waitcnt vmcnt(0)" ::: "memory");
                __builtin_amdgcn_sched_barrier(0);
                const float* wf = &wfc_s[kc * 32 + l4 * 8];
                unsigned int uu[4] = {va.u.x, va.u.y, va.u.z, va.u.w};
                unsigned int ll[4] = {vb.u.x, vb.u.y, vb.u.z, vb.u.w};
                #pragma unroll
                for (int i = 0; i < 4; ++i) {
                    float h0 = __uint_as_float(uu[i] << 16)
                             + __uint_as_float(ll[i] << 16);
                    float h1 = __uint_as_float(uu[i] & 0xffff0000u)
                             + __uint_as_float(ll[i] & 0xffff0000u);
                    dsum = fmaf(h0, wf[2 * i + 0], dsum);
                    dsum = fmaf(h1, wf[2 * i + 1], dsum);
                }
            }
            dsum += __shfl_xor(dsum, 16);
            dsum += __shfl_xor(dsum, 32);
            if (lane < 16)
                out[(size_t)(bbase + mt * 16 + lane) * TLEN + (TLEN - 1)] = dsum + bfc;
        }
    }
}

// ================= fallback (r8 kernel, needs no workspace) =================
#define BB 32
__global__ __launch_bounds__(NTHR, 4) void lstm_mfma7(
    const float* __restrict__ x, const float* __restrict__ W_ih,
    const float* __restrict__ W_hh, const float* __restrict__ b_ih,
    const float* __restrict__ b_hh, const float* __restrict__ W_fc,
    const float* __restrict__ b_fc, float* __restrict__ out)
{
    const int tid = threadIdx.x;
    const int wave = tid >> 6;
    const int lane = tid & 63;
    const int l15 = lane & 15;
    const int l4 = lane >> 4;
    const int bbase = blockIdx.x * BB;

    __shared__ unsigned short hhi[2][16 * 512];
    __shared__ unsigned short hlo[2][16 * 512];
    __shared__ float dpart[16][BB];
    __shared__ float inp_s[BB];

    for (int i = tid; i < 16 * 512; i += NTHR) { hhi[0][i] = 0; hlo[0][i] = 0; }
    if (tid < BB) inp_s[tid] = x[bbase + tid];

    float biasv[4], wihv[4];
    #pragma unroll
    for (int q = 0; q < 4; ++q) {
        int gg = 256 * q + 16 * wave + l15;
        biasv[q] = b_ih[gg] + b_hh[gg];
        wihv[q] = W_ih[gg];
    }
    const float wfc = W_fc[16 * wave + l15];
    const float bfc = b_fc[0];
    const float* __restrict__ wrow = W_hh + (size_t)(16 * wave + l15) * HID + l4 * 8;
    const int kc_w = wave >> 1;
    const int kwhi = (wave & 1) * 2 + (l15 >> 3);
    const int elemw = l15 & 7;

    float c_r[2][4];
    #pragma unroll
    for (int m = 0; m < 2; ++m)
        #pragma unroll
        for (int r = 0; r < 4; ++r) c_r[m][r] = 0.0f;
    __syncthreads();

    #pragma unroll 1
    for (int t = 0; t < TLEN; ++t) {
        const int p = t & 1;
        f32x4 acc[2][4];
        {
            float dv[2][4];
            #pragma unroll
            for (int m = 0; m < 2; ++m)
                #pragma unroll
                for (int r = 0; r < 4; ++r) dv[m][r] = inp_s[16 * m + 4 * l4 + r];
            #pragma unroll
            for (int m = 0; m < 2; ++m)
                #pragma unroll
                for (int q = 0; q < 4; ++q)
                    #pragma unroll
                    for (int r = 0; r < 4; ++r)
                        acc[m][q][r] = fmaf(dv[m][r], wihv[q], biasv[q]);
        }
        #pragma unroll
        for (int kc = 0; kc < 8; ++kc) {
            short8 ahi[2], alo[2];
            #pragma unroll
            for (int m = 0; m < 2; ++m) {
                int aoff = (m * 8 + kc) * 512 + lane * 8;
                ahi[m] = *(const short8*)&hhi[p][aoff];
                alo[m] = *(const short8*)&hlo[p][aoff];
            }
            #pragma unroll
            for (int q = 0; q < 4; ++q) {
                const float* src = wrow + (size_t)q * 256 * HID + kc * 32;
                float4 wa = *(const float4*)src;
                float4 wb = *(const float4*)(src + 4);
                float ff[8] = {wa.x, wa.y, wa.z, wa.w, wb.x, wb.y, wb.z, wb.w};
                short8 bhi, blo;
                #pragma unroll
                for (int e = 0; e < 8; ++e) {
                    unsigned int u = __float_as_uint(ff[e]);
                    bhi[e] = (short)(u >> 16);
                    float res = ff[e] - __uint_as_float(u & 0xffff0000u);
                    blo[e] = (short)(__float_as_uint(res) >> 16);
                }
                #pragma unroll
                for (int m = 0; m < 2; ++m) {
                    acc[m][q] = __builtin_amdgcn_mfma_f32_16x16x32_bf16(ahi[m], bhi, acc[m][q], 0, 0, 0);
                    acc[m][q] = __builtin_amdgcn_mfma_f32_16x16x32_bf16(alo[m], bhi, acc[m][q], 0, 0, 0);
                    acc[m][q] = __builtin_amdgcn_mfma_f32_16x16x32_bf16(ahi[m], blo, acc[m][q], 0, 0, 0);
                }
            }
        }
        #pragma unroll
        for (int m = 0; m < 2; ++m) {
            #pragma unroll
            for (int r = 0; r < 4; ++r) {
                float gi = acc[m][0][r];
                float gf = acc[m][1][r];
                float gg = acc[m][2][r];
                float go = acc[m][3][r];
                float c = fmaf(sigf(gf), c_r[m][r], sigf(gi) * tanhf_fast(gg));
                c_r[m][r] = c;
                float h = sigf(go) * tanhf_fast(c);
                unsigned short hh = f2bf_rne(h);
                float hres = h - __uint_as_float(__float_as_uint(h) & 0xffff0000u);
                int haddr = (m * 8 + kc_w) * 512 + ((4 * l4 + r) + 16 * kwhi) * 8 + elemw;
                hhi[p ^ 1][haddr] = hh;
                hlo[p ^ 1][haddr] = f2bf_rne(hres);
                float s = h * wfc;
                s += __shfl_xor(s, 1);
                s += __shfl_xor(s, 2);
                s += __shfl_xor(s, 4);
                s += __shfl_xor(s, 8);
                if (l15 == 0) dpart[wave][16 * m + 4 * l4 + r] = s;
            }
        }
        __syncthreads();
        if (tid < BB) {
            float s = bfc;
            #pragma unroll
            for (int w = 0; w < 16; ++w) s += dpart[w][tid];
            inp_s[tid] = s;
            out[(size_t)(bbase + tid) * TLEN + t] = s;
        }
        __syncthreads();
    }
}

extern "C" void kernel_launch(void* const* d_in, const int* in_sizes, int n_in,
                              void* d_out, int out_size, void* d_ws, size_t ws_size,
                              hipStream_t stream) {
    const float* x    = (const float*)d_in[0];
    const float* W_ih = (const float*)d_in[1];
    const float* W_hh = (const float*)d_in[2];
    const float* b_ih = (const float*)d_in[3];
    const float* b_hh = (const float*)d_in[4];
    const float* W_fc = (const float*)d_in[5];
    const float* b_fc = (const float*)d_in[6];
    float* out = (float*)d_out;

    const int BATCH = in_sizes[0];   // 8192

    if (ws_size >= WS_NEEDED) {
        unsigned int* flags = (unsigned int*)((char*)d_ws + FLAGS_OFF);
        init_flags<<<1, 256, 0, stream>>>(flags);
        lstm_coop7<<<BATCH / BBG * GSIZE, NTHR, 0, stream>>>(
            x, W_ih, W_hh, b_ih, b_hh, W_fc, b_fc,
            (unsigned short*)d_ws, flags, out);
    } else {
        lstm_mfma7<<<BATCH / BB, NTHR, 0, stream>>>(
            x, W_ih, W_hh, b_ih, b_hh, W_fc, b_fc, out);
    }
}

// Round 15
// 7848.192 us; speedup vs baseline: 2.0323x; 1.0567x over previous
//
#include <hip/hip_runtime.h>
#include <math.h>

#define HID   256
#define TLEN  512
#define NTHR  1024
#define GSIZE 8
#define NGRP  32
#define BBG   256            // batches per group

// h exchange: [NGRP][2 bufs][2 sel(hi,lo)][65536 u16]  (A-fragment order)
#define PLANE_U16 (16 * 8 * 512)                        // 65536 u16 = 128 KiB
#define HEX_U16   ((size_t)NGRP * 2 * 2 * PLANE_U16)    // 8M u16 = 16 MiB
#define FLAGS_OFF (HEX_U16 * 2)                         // bytes
#define NFLAGS    (NGRP * GSIZE)
#define WS_NEEDED (FLAGS_OFF + (size_t)NFLAGS * 4)

typedef __attribute__((ext_vector_type(8))) short short8;
typedef __attribute__((ext_vector_type(4))) float f32x4;

typedef union {
    float4 f;
    uint4  u;
    short8 s;
} v16u;

static __device__ __forceinline__ unsigned short f2bf_rne(float x) {
    unsigned int u = __float_as_uint(x);
    unsigned int r = (u + 0x7FFFu + ((u >> 16) & 1u)) >> 16;
    return (unsigned short)r;
}
static __device__ __forceinline__ float sigf(float x) {
    return 1.0f / (1.0f + __expf(-x));
}
static __device__ __forceinline__ float tanhf_fast(float x) {
    return 1.0f - 2.0f / (1.0f + __expf(2.0f * x));
}

// ---- device-coherent (MALL-level) memory ops: sc0 sc1 = bypass L1 and L2 ----
static __device__ __forceinline__ void issue_dev(const void* p, float4& a) {
    asm volatile("global_load_dwordx4 %0, %1, off sc0 sc1"
                 : "=&v"(a) : "v"(p) : "memory");
}
static __device__ __forceinline__ void store_short_dev(void* p, unsigned int v) {
    asm volatile("global_store_short %0, %1, off sc0 sc1"
                 :: "v"(p), "v"(v) : "memory");
}
static __device__ __forceinline__ unsigned int load_flag_dev(const unsigned int* p) {
    unsigned int v;
    asm volatile("global_load_dword %0, %1, off sc0 sc1\n\t"
                 "s_waitcnt vmcnt(0)"
                 : "=v"(v) : "v"(p) : "memory");
    return v;
}
static __device__ __forceinline__ void store_flag_dev(unsigned int* p, unsigned int v) {
    asm volatile("global_store_dword %0, %1, off sc0 sc1"
                 :: "v"(p), "v"(v) : "memory");
}

// flags init: device-coherent zeroing (replay-safe)
__global__ void init_flags(unsigned int* flags) {
    int i = blockIdx.x * 256 + threadIdx.x;
    if (i < NFLAGS) store_flag_dev(flags + i, 0u);
}

// ================= cooperative weight-stationary kernel =================
__global__ __launch_bounds__(NTHR, 4) void lstm_coop8(
    const float* __restrict__ x,
    const float* __restrict__ W_ih,
    const float* __restrict__ W_hh,
    const float* __restrict__ b_ih,
    const float* __restrict__ b_hh,
    const float* __restrict__ W_fc,
    const float* __restrict__ b_fc,
    unsigned short* __restrict__ hexw,  // ws: split-bf16 h exchange planes
    unsigned int* __restrict__ flags,   // ws: [NGRP][GSIZE], init by init_flags
    float* __restrict__ out)
{
    const int tid  = threadIdx.x;
    const int bid  = blockIdx.x;
    const int xcd  = bid & 7;
    const int p    = (bid >> 3) & 7;   // producer index within group
    const int gsub = bid >> 6;         // 0..3
    const int g    = xcd * 4 + gsub;   // group 0..31
    const int bbase = g * BBG;
    const int mt   = tid >> 6;         // wave = M-tile (16 batches)
    const int lane = tid & 63;
    const int l15  = lane & 15;
    const int l4   = lane >> 4;

    __shared__ unsigned short whi_s[64 * 512];   // 64 KiB  gate B-frags hi
    __shared__ unsigned short wlo_s[64 * 512];   // 64 KiB  gate B-frags lo
    __shared__ unsigned short fhi_s[8 * 512];    // 8 KiB   wfc B-frags hi (col 0)
    __shared__ unsigned short flo_s[8 * 512];    // 8 KiB   wfc B-frags lo
    __shared__ float wfc_s[HID];                 // for epilogue only

    // ---- stage this block's 128 gate-rows into LDS (split bf16, B-frag order) ----
    #pragma unroll
    for (int i = 0; i < 4; ++i) {
        int tile = mt * 4 + i;            // 0..63 = nt*8 + kc
        int nt = tile >> 3, kc = tile & 7;
        int q = nt >> 1, half = nt & 1;
        int grow = q * 256 + p * 32 + half * 16 + l15;
        int k0 = kc * 32 + l4 * 8;
        const float* src = W_hh + (size_t)grow * HID + k0;
        float4 wa = *(const float4*)src;
        float4 wb = *(const float4*)(src + 4);
        float ff[8] = {wa.x, wa.y, wa.z, wa.w, wb.x, wb.y, wb.z, wb.w};
        short8 hi8, lo8;
        #pragma unroll
        for (int e = 0; e < 8; ++e) {
            unsigned int u = __float_as_uint(ff[e]);
            hi8[e] = (short)(u >> 16);
            float res = ff[e] - __uint_as_float(u & 0xffff0000u);
            lo8[e] = (short)f2bf_rne(res);
        }
        *(short8*)&whi_s[tile * 512 + lane * 8] = hi8;
        *(short8*)&wlo_s[tile * 512 + lane * 8] = lo8;
    }
    // ---- stage wfc B-frags: column n=0 holds W_fc, other columns zero ----
    if (mt < 8) {
        int kc = mt;
        short8 fh = {0,0,0,0,0,0,0,0};
        short8 fl = {0,0,0,0,0,0,0,0};
        if (l15 == 0) {
            #pragma unroll
            for (int e = 0; e < 8; ++e) {
                float wv = W_fc[kc * 32 + l4 * 8 + e];
                unsigned int u = __float_as_uint(wv);
                fh[e] = (short)(u >> 16);
                float res = wv - __uint_as_float(u & 0xffff0000u);
                fl[e] = (short)f2bf_rne(res);
            }
        }
        *(short8*)&fhi_s[kc * 512 + lane * 8] = fh;
        *(short8*)&flo_s[kc * 512 + lane * 8] = fl;
    }
    if (tid < HID) wfc_s[tid] = W_fc[tid];

    // per-lane gate constants: nt = q*2+half -> grow
    float biasv[8], wihv[8];
    #pragma unroll
    for (int nt = 0; nt < 8; ++nt) {
        int grow = (nt >> 1) * 256 + p * 32 + (nt & 1) * 16 + l15;
        biasv[nt] = b_ih[grow] + b_hh[grow];
        wihv[nt]  = W_ih[grow];
    }
    const float bfc = b_fc[0];

    float c_r[2][4];
    #pragma unroll
    for (int half = 0; half < 2; ++half)
        #pragma unroll
        for (int r = 0; r < 4; ++r) c_r[half][r] = 0.0f;

    unsigned int* flg = flags + g * GSIZE;
    unsigned short* const gbase = hexw + (size_t)g * 4 * PLANE_U16;
    // plane(buf,sel) = gbase + (buf*2+sel)*PLANE_U16

    __syncthreads();

    // ================= step 0: gates = bias + x*wih (h=0) =================
    {
        float dreg[4];
        #pragma unroll
        for (int r = 0; r < 4; ++r) dreg[r] = x[bbase + mt * 16 + l4 * 4 + r];

        unsigned short* hiw = gbase + (1 * 2 + 0) * PLANE_U16;  // h(1) -> buf 1
        unsigned short* low = gbase + (1 * 2 + 1) * PLANE_U16;
        #pragma unroll
        for (int half = 0; half < 2; ++half) {
            #pragma unroll
            for (int r = 0; r < 4; ++r) {
                float gi = fmaf(dreg[r], wihv[0 + half], biasv[0 + half]);
                float gf = fmaf(dreg[r], wihv[2 + half], biasv[2 + half]);
                float gg = fmaf(dreg[r], wihv[4 + half], biasv[4 + half]);
                float go = fmaf(dreg[r], wihv[6 + half], biasv[6 + half]);
                float c = fmaf(sigf(gf), c_r[half][r], sigf(gi) * tanhf_fast(gg));
                c_r[half][r] = c;
                float h = sigf(go) * tanhf_fast(c);
                int lane_d = l4 * 4 + r + 16 * (half * 2 + (l15 >> 3));
                int idx = (mt * 8 + p) * 512 + lane_d * 8 + (l15 & 7);
                unsigned int u = __float_as_uint(h);
                store_short_dev(hiw + idx, u >> 16);
                float res = h - __uint_as_float(u & 0xffff0000u);
                store_short_dev(low + idx, (unsigned int)f2bf_rne(res));
            }
        }
        asm volatile("s_waitcnt vmcnt(0)" ::: "memory");   // h at MALL
        __syncthreads();                                   // all waves drained
        if (tid == 0) store_flag_dev(&flg[p], 1u);
    }

    // ================= steps 1..511 =================
    #pragma unroll 1
    for (int t = 1; t < TLEN; ++t) {
        // wait for all 8 shares of h(t)
        if (tid < GSIZE) {
            int guard = 0;
            while (load_flag_dev(&flg[tid]) < (unsigned int)t) {
                if (++guard > (1 << 18)) break;   // failsafe: never hang
            }
        }
        __syncthreads();

        const unsigned short* hir = gbase + ((t & 1) * 2 + 0) * PLANE_U16
                                  + (mt * 8) * 512 + lane * 8;
        const unsigned short* lor = gbase + ((t & 1) * 2 + 1) * PLANE_U16
                                  + (mt * 8) * 512 + lane * 8;

        f32x4 acc[8];
        #pragma unroll
        for (int nt = 0; nt < 8; ++nt)
            #pragma unroll
            for (int r = 0; r < 4; ++r) acc[nt][r] = 0.0f;
        f32x4 accd = {0.0f, 0.0f, 0.0f, 0.0f};   // d-column accumulator

        v16u pfh[3], pfl[3];
        issue_dev(hir, pfh[0].f);
        issue_dev(lor, pfl[0].f);
        issue_dev(hir + 512, pfh[1].f);
        issue_dev(lor + 512, pfl[1].f);

        #pragma unroll
        for (int kc = 0; kc < 8; ++kc) {
            if (kc < 6) {
                issue_dev(hir + (kc + 2) * 512, pfh[(kc + 2) % 3].f);
                issue_dev(lor + (kc + 2) * 512, pfl[(kc + 2) % 3].f);
                asm volatile("s_waitcnt vmcnt(4)" ::: "memory");
            } else if (kc == 6) {
                asm volatile("s_waitcnt vmcnt(2)" ::: "memory");
            } else {
                asm volatile("s_waitcnt vmcnt(0)" ::: "memory");
            }
            __builtin_amdgcn_sched_barrier(0);

            const v16u ha = pfh[kc % 3];
            const v16u la = pfl[kc % 3];

            #pragma unroll
            for (int nt = 0; nt < 8; ++nt) {
                short8 bhi = *(const short8*)&whi_s[(nt * 8 + kc) * 512 + lane * 8];
                short8 blo = *(const short8*)&wlo_s[(nt * 8 + kc) * 512 + lane * 8];
                acc[nt] = __builtin_amdgcn_mfma_f32_16x16x32_bf16(ha.s, bhi, acc[nt], 0, 0, 0);
                acc[nt] = __builtin_amdgcn_mfma_f32_16x16x32_bf16(la.s, bhi, acc[nt], 0, 0, 0);
                acc[nt] = __builtin_amdgcn_mfma_f32_16x16x32_bf16(ha.s, blo, acc[nt], 0, 0, 0);
            }
            // d-column MFMAs: B holds wfc in col 0
            {
                short8 fh = *(const short8*)&fhi_s[kc * 512 + lane * 8];
                short8 fl = *(const short8*)&flo_s[kc * 512 + lane * 8];
                accd = __builtin_amdgcn_mfma_f32_16x16x32_bf16(ha.s, fh, accd, 0, 0, 0);
                accd = __builtin_amdgcn_mfma_f32_16x16x32_bf16(la.s, fh, accd, 0, 0, 0);
                accd = __builtin_amdgcn_mfma_f32_16x16x32_bf16(ha.s, fl, accd, 0, 0, 0);
            }
        }

        // d(t-1): lanes with l15==0 hold col 0 = d for batch mt*16 + l4*4 + r
        if (p == 0 && l15 == 0) {
            #pragma unroll
            for (int r = 0; r < 4; ++r)
                out[(size_t)(bbase + mt * 16 + l4 * 4 + r) * TLEN + (t - 1)] = accd[r] + bfc;
        }
        float dreg[4];
        #pragma unroll
        for (int r = 0; r < 4; ++r)
            dreg[r] = __shfl(accd[r], lane & 48) + bfc;   // broadcast from l15==0 lane

        // cell update + h(t+1) split store (device-coherent)
        unsigned short* hiw = gbase + ((((t + 1) & 1)) * 2 + 0) * PLANE_U16;
        unsigned short* low = gbase + ((((t + 1) & 1)) * 2 + 1) * PLANE_U16;
        #pragma unroll
        for (int half = 0; half < 2; ++half) {
            #pragma unroll
            for (int r = 0; r < 4; ++r) {
                float gi = acc[0 + half][r] + fmaf(dreg[r], wihv[0 + half], biasv[0 + half]);
                float gf = acc[2 + half][r] + fmaf(dreg[r], wihv[2 + half], biasv[2 + half]);
                float gg = acc[4 + half][r] + fmaf(dreg[r], wihv[4 + half], biasv[4 + half]);
                float go = acc[6 + half][r] + fmaf(dreg[r], wihv[6 + half], biasv[6 + half]);
                float c = fmaf(sigf(gf), c_r[half][r], sigf(gi) * tanhf_fast(gg));
                c_r[half][r] = c;
                float h = sigf(go) * tanhf_fast(c);
                int lane_d = l4 * 4 + r + 16 * (half * 2 + (l15 >> 3));
                int idx = (mt * 8 + p) * 512 + lane_d * 8 + (l15 & 7);
                unsigned int u = __float_as_uint(h);
                store_short_dev(hiw + idx, u >> 16);
                float res = h - __uint_as_float(u & 0xffff0000u);
                store_short_dev(low + idx, (unsigned int)f2bf_rne(res));
            }
        }
        asm volatile("s_waitcnt vmcnt(0)" ::: "memory");   // h at MALL
        __syncthreads();                                   // all waves drained
        if (tid == 0) store_flag_dev(&flg[p], (unsigned int)(t + 1));
    }

    // ================= epilogue: out[:,511] = h(512)·wfc + bfc =================
    {
        if (tid < GSIZE) {
            int guard = 0;
            while (load_flag_dev(&flg[tid]) < (unsigned int)TLEN) {
                if (++guard > (1 << 18)) break;
            }
        }
        __syncthreads();
        if (p == 0) {
            const unsigned short* hir = gbase + (0 * 2 + 0) * PLANE_U16
                                      + (mt * 8) * 512 + lane * 8;
            const unsigned short* lor = gbase + (0 * 2 + 1) * PLANE_U16
                                      + (mt * 8) * 512 + lane * 8;
            float dsum = 0.0f;
            #pragma unroll
            for (int kc = 0; kc < 8; ++kc) {
                v16u va, vb;
                issue_dev(hir + kc * 512, va.f);
                issue_dev(lor + kc * 512, vb.f);
                asm volatile("s_waitcnt vmcnt(0)" ::: "memory");
                __builtin_amdgcn_sched_barrier(0);
                const float* wf = &wfc_s[kc * 32 + l4 * 8];
                unsigned int uu[4] = {va.u.x, va.u.y, va.u.z, va.u.w};
                unsigned int ll[4] = {vb.u.x, vb.u.y, vb.u.z, vb.u.w};
                #pragma unroll
                for (int i = 0; i < 4; ++i) {
                    float h0 = __uint_as_float(uu[i] << 16)
                             + __uint_as_float(ll[i] << 16);
                    float h1 = __uint_as_float(uu[i] & 0xffff0000u)
                             + __uint_as_float(ll[i] & 0xffff0000u);
                    dsum = fmaf(h0, wf[2 * i + 0], dsum);
                    dsum = fmaf(h1, wf[2 * i + 1], dsum);
                }
            }
            dsum += __shfl_xor(dsum, 16);
            dsum += __shfl_xor(dsum, 32);
            if (lane < 16)
                out[(size_t)(bbase + mt * 16 + lane) * TLEN + (TLEN - 1)] = dsum + bfc;
        }
    }
}

// ================= fallback (r8 kernel, needs no workspace) =================
#define BB 32
__global__ __launch_bounds__(NTHR, 4) void lstm_mfma7(
    const float* __restrict__ x, const float* __restrict__ W_ih,
    const float* __restrict__ W_hh, const float* __restrict__ b_ih,
    const float* __restrict__ b_hh, const float* __restrict__ W_fc,
    const float* __restrict__ b_fc, float* __restrict__ out)
{
    const int tid = threadIdx.x;
    const int wave = tid >> 6;
    const int lane = tid & 63;
    const int l15 = lane & 15;
    const int l4 = lane >> 4;
    const int bbase = blockIdx.x * BB;

    __shared__ unsigned short hhi[2][16 * 512];
    __shared__ unsigned short hlo[2][16 * 512];
    __shared__ float dpart[16][BB];
    __shared__ float inp_s[BB];

    for (int i = tid; i < 16 * 512; i += NTHR) { hhi[0][i] = 0; hlo[0][i] = 0; }
    if (tid < BB) inp_s[tid] = x[bbase + tid];

    float biasv[4], wihv[4];
    #pragma unroll
    for (int q = 0; q < 4; ++q) {
        int gg = 256 * q + 16 * wave + l15;
        biasv[q] = b_ih[gg] + b_hh[gg];
        wihv[q] = W_ih[gg];
    }
    const float wfc = W_fc[16 * wave + l15];
    const float bfc = b_fc[0];
    const float* __restrict__ wrow = W_hh + (size_t)(16 * wave + l15) * HID + l4 * 8;
    const int kc_w = wave >> 1;
    const int kwhi = (wave & 1) * 2 + (l15 >> 3);
    const int elemw = l15 & 7;

    float c_r[2][4];
    #pragma unroll
    for (int m = 0; m < 2; ++m)
        #pragma unroll
        for (int r = 0; r < 4; ++r) c_r[m][r] = 0.0f;
    __syncthreads();

    #pragma unroll 1
    for (int t = 0; t < TLEN; ++t) {
        const int p = t & 1;
        f32x4 acc[2][4];
        {
            float dv[2][4];
            #pragma unroll
            for (int m = 0; m < 2; ++m)
                #pragma unroll
                for (int r = 0; r < 4; ++r) dv[m][r] = inp_s[16 * m + 4 * l4 + r];
            #pragma unroll
            for (int m = 0; m < 2; ++m)
                #pragma unroll
                for (int q = 0; q < 4; ++q)
                    #pragma unroll
                    for (int r = 0; r < 4; ++r)
                        acc[m][q][r] = fmaf(dv[m][r], wihv[q], biasv[q]);
        }
        #pragma unroll
        for (int kc = 0; kc < 8; ++kc) {
            short8 ahi[2], alo[2];
            #pragma unroll
            for (int m = 0; m < 2; ++m) {
                int aoff = (m * 8 + kc) * 512 + lane * 8;
                ahi[m] = *(const short8*)&hhi[p][aoff];
                alo[m] = *(const short8*)&hlo[p][aoff];
            }
            #pragma unroll
            for (int q = 0; q < 4; ++q) {
                const float* src = wrow + (size_t)q * 256 * HID + kc * 32;
                float4 wa = *(const float4*)src;
                float4 wb = *(const float4*)(src + 4);
                float ff[8] = {wa.x, wa.y, wa.z, wa.w, wb.x, wb.y, wb.z, wb.w};
                short8 bhi, blo;
                #pragma unroll
                for (int e = 0; e < 8; ++e) {
                    unsigned int u = __float_as_uint(ff[e]);
                    bhi[e] = (short)(u >> 16);
                    float res = ff[e] - __uint_as_float(u & 0xffff0000u);
                    blo[e] = (short)(__float_as_uint(res) >> 16);
                }
                #pragma unroll
                for (int m = 0; m < 2; ++m) {
                    acc[m][q] = __builtin_amdgcn_mfma_f32_16x16x32_bf16(ahi[m], bhi, acc[m][q], 0, 0, 0);
                    acc[m][q] = __builtin_amdgcn_mfma_f32_16x16x32_bf16(alo[m], bhi, acc[m][q], 0, 0, 0);
                    acc[m][q] = __builtin_amdgcn_mfma_f32_16x16x32_bf16(ahi[m], blo, acc[m][q], 0, 0, 0);
                }
            }
        }
        #pragma unroll
        for (int m = 0; m < 2; ++m) {
            #pragma unroll
            for (int r = 0; r < 4; ++r) {
                float gi = acc[m][0][r];
                float gf = acc[m][1][r];
                float gg = acc[m][2][r];
                float go = acc[m][3][r];
                float c = fmaf(sigf(gf), c_r[m][r], sigf(gi) * tanhf_fast(gg));
                c_r[m][r] = c;
                float h = sigf(go) * tanhf_fast(c);
                unsigned short hh = f2bf_rne(h);
                float hres = h - __uint_as_float(__float_as_uint(h) & 0xffff0000u);
                int haddr = (m * 8 + kc_w) * 512 + ((4 * l4 + r) + 16 * kwhi) * 8 + elemw;
                hhi[p ^ 1][haddr] = hh;
                hlo[p ^ 1][haddr] = f2bf_rne(hres);
                float s = h * wfc;
                s += __shfl_xor(s, 1);
                s += __shfl_xor(s, 2);
                s += __shfl_xor(s, 4);
                s += __shfl_xor(s, 8);
                if (l15 == 0) dpart[wave][16 * m + 4 * l4 + r] = s;
            }
        }
        __syncthreads();
        if (tid < BB) {
            float s = bfc;
            #pragma unroll
            for (int w = 0; w < 16; ++w) s += dpart[w][tid];
            inp_s[tid] = s;
            out[(size_t)(bbase + tid) * TLEN + t] = s;
        }
        __syncthreads();
    }
}

extern "C" void kernel_launch(void* const* d_in, const int* in_sizes, int n_in,
                              void* d_out, int out_size, void* d_ws, size_t ws_size,
                              hipStream_t stream) {
    const float* x    = (const float*)d_in[0];
    const float* W_ih = (const float*)d_in[1];
    const float* W_hh = (const float*)d_in[2];
    const float* b_ih = (const float*)d_in[3];
    const float* b_hh = (const float*)d_in[4];
    const float* W_fc = (const float*)d_in[5];
    const float* b_fc = (const float*)d_in[6];
    float* out = (float*)d_out;

    const int BATCH = in_sizes[0];   // 8192

    if (ws_size >= WS_NEEDED) {
        unsigned int* flags = (unsigned int*)((char*)d_ws + FLAGS_OFF);
        init_flags<<<1, 256, 0, stream>>>(flags);
        lstm_coop8<<<BATCH / BBG * GSIZE, NTHR, 0, stream>>>(
            x, W_ih, W_hh, b_ih, b_hh, W_fc, b_fc,
            (unsigned short*)d_ws, flags, out);
    } else {
        lstm_mfma7<<<BATCH / BB, NTHR, 0, stream>>>(
            x, W_ih, W_hh, b_ih, b_hh, W_fc, b_fc, out);
    }
}